// Round 8
// baseline (108.733 us; speedup 1.0000x reference)
//
#include <hip/hip_runtime.h>

// Problem constants (match reference)
constexpr int B    = 64;
constexpr int E    = 512;
constexpr int P    = 31;    // patch size
constexpr int S    = 200;   // canvas size
constexpr int HALF = 15;

// Tiling
constexpr int TS     = 16;
constexpr int NTD    = (S + TS - 1) / TS;    // 13 tiles per dim
constexpr int NTILES = NTD * NTD;            // 169 tiles per batch
constexpr int NBINS  = B * NTILES;           // 10816
constexpr int CAP    = 128;                  // bin capacity (expected ~38, max ~65)

// Gather launch: one wave per tile, 4 tiles per 256-thread block
constexpr int TPB     = 4;
constexpr int THREADS = 256;
constexpr int NBLK    = (NTILES + TPB - 1) / TPB;   // 43

// 4-float load with only 4-byte alignment guarantee (patch row stride = 31 floats)
struct alignas(4) F4 { float v[4]; };

__global__ __launch_bounds__(512)
void imgs4dto3d_bin_kernel(const int* __restrict__ xyz,
                           int*       __restrict__ counts,
                           unsigned*  __restrict__ entries)
{
    const int b = blockIdx.x;
    const int e = threadIdx.x;
    const int x = xyz[(size_t)(b * E + e) * 3 + 0];
    const int y = xyz[(size_t)(b * E + e) * 3 + 1];
    const unsigned pk = (unsigned)e | ((unsigned)x << 9) | ((unsigned)y << 17);

    const int tr_lo = (x - HALF) >> 4, tr_hi = (x + HALF) >> 4;
    const int tc_lo = (y - HALF) >> 4, tc_hi = (y + HALF) >> 4;

    for (int tr = tr_lo; tr <= tr_hi; ++tr) {
        for (int tc = tc_lo; tc <= tc_hi; ++tc) {
            const int bin = b * NTILES + tr * NTD + tc;
            const int pos = atomicAdd(&counts[bin], 1);
            if (pos < CAP) entries[(size_t)bin * CAP + pos] = pk;
        }
    }
}

__global__ __launch_bounds__(THREADS, 8)
void imgs4dto3d_gather_kernel(const float*    __restrict__ img,
                              const int*      __restrict__ counts,
                              const unsigned* __restrict__ entries,
                              float*          __restrict__ out)
{
    const int b    = blockIdx.y;
    const int tid  = threadIdx.x;
    const int wid  = tid >> 6;
    const int lane = tid & 63;

    const int t    = blockIdx.x * TPB + wid;
    const bool live = (t < NTILES);
    const int tr = live ? (t / NTD) : 0;
    const int tc = live ? (t % NTD) : 0;
    const int r0 = tr * TS;
    const int c0 = tc * TS;

    // lane = (row 0..15) x (colgroup 0..3); consecutive lanes -> contiguous 16 floats/row
    const int cg   = lane & 3;
    const int r    = lane >> 2;
    const int rowc = r0 + r;            // canvas row this lane owns
    const int colc = c0 + 4 * cg;       // canvas col base (4 cols via float4)

    const int bin = live ? (b * NTILES + t) : 0;
    int n = live ? counts[bin] : 0;
    n = min(n, CAP);
    const uint4* lst = reinterpret_cast<const uint4*>(entries + (size_t)bin * CAP);

    const int rr = rowc + HALF;         // pr  = rr - x
    const int cc = colc + HALF;         // pc0 = cc - y

    float a0 = 0.f, a1 = 0.f, a2 = 0.f, a3 = 0.f;
    const float* imgb = img + (size_t)b * E * (P * P);
    constexpr int MAXOFF = E * P * P - 4;   // window [off,off+3] in-slab iff off<=MAXOFF
    constexpr int LAST   = E * P * P - 1;

    const int niter = (n + 3) >> 2;
    uint4 cur = (niter > 0) ? lst[0] : make_uint4(0u, 0u, 0u, 0u);
    for (int i = 0; i < niter; ++i) {
        const uint4 nxt = (i + 1 < niter) ? lst[i + 1] : cur;
        const unsigned pks[4] = {cur.x, cur.y, cur.z, cur.w};
        #pragma unroll
        for (int u = 0; u < 4; ++u) {
            const bool inb = (4 * i + u) < n;        // wave-uniform
            const unsigned pk = pks[u];
            const int e = (int)(pk & 511u);
            const int x = (int)((pk >> 9) & 255u);
            const int y = (int)(pk >> 17);

            const int pr  = rr - x;                  // patch row (verified math)
            const int pc0 = cc - y;                  // patch col of component 0
            const bool rok = inb && ((unsigned)pr <= 30u);

            const int off = e * (P * P) + pr * P + pc0;

            F4 vv;
            if ((unsigned)off <= (unsigned)MAXOFF) {
                // fast path: whole 16B window inside the batch slab
                vv = *reinterpret_cast<const F4*>(imgb + off);
            } else {
                // rare slab-edge case: per-component clamped loads.
                // clamp is identity for every component whose mask is true.
                #pragma unroll
                for (int j = 0; j < 4; ++j)
                    vv.v[j] = imgb[min(max(off + j, 0), LAST)];
            }

            const bool m0 = rok && ((unsigned)(pc0 + 0) <= 30u);
            const bool m1 = rok && ((unsigned)(pc0 + 1) <= 30u);
            const bool m2 = rok && ((unsigned)(pc0 + 2) <= 30u);
            const bool m3 = rok && ((unsigned)(pc0 + 3) <= 30u);
            a0 += m0 ? vv.v[0] : 0.f;
            a1 += m1 ? vv.v[1] : 0.f;
            a2 += m2 ? vv.v[2] : 0.f;
            a3 += m3 ? vv.v[3] : 0.f;
        }
        cur = nxt;
    }

    // store: one aligned float4 per lane; every canvas pixel written exactly once
    if (live && rowc < S && colc < S) {   // colc multiple of 4 -> cols colc..colc+3 all < S
        *reinterpret_cast<float4*>(out + (size_t)b * (S * S) + rowc * S + colc) =
            make_float4(a0, a1, a2, a3);
    }
}

extern "C" void kernel_launch(void* const* d_in, const int* in_sizes, int n_in,
                              void* d_out, int out_size, void* d_ws, size_t ws_size,
                              hipStream_t stream)
{
    const float* img = (const float*)d_in[0];   // [B, E, P, P] fp32
    const int*   xyz = (const int*)d_in[1];     // [B, E, 3] int32
    float*       out = (float*)d_out;           // [B, 1, S, S] fp32

    int*      counts  = (int*)d_ws;
    unsigned* entries = (unsigned*)d_ws + NBINS;

    hipMemsetAsync(counts, 0, (size_t)NBINS * sizeof(int), stream);

    imgs4dto3d_bin_kernel<<<B, E, 0, stream>>>(xyz, counts, entries);

    dim3 grid(NBLK, B);
    imgs4dto3d_gather_kernel<<<grid, THREADS, 0, stream>>>(img, counts, entries, out);
}

// Round 9
// 89.545 us; speedup vs baseline: 1.2143x; 1.2143x over previous
//
#include <hip/hip_runtime.h>

// Problem constants (match reference)
constexpr int B    = 64;
constexpr int E    = 512;
constexpr int P    = 31;    // patch size
constexpr int S    = 200;   // canvas size
constexpr int HALF = 15;

// Tiling: 32 rows x 16 cols per tile
constexpr int TRZ    = 32;
constexpr int TCZ    = 16;
constexpr int NTR    = (S + TRZ - 1) / TRZ;   // 7
constexpr int NTC    = (S + TCZ - 1) / TCZ;   // 13
constexpr int NTILES = NTR * NTC;             // 91 per batch
constexpr int NBINS  = B * NTILES;            // 5824
constexpr int CAP    = 128;                   // bin capacity (mean ~37, max ~65)

// Gather launch: one wave per tile, 4 tiles per 256-thread block
constexpr int TPB     = 4;
constexpr int THREADS = 256;
constexpr int NBLK    = (NTILES + TPB - 1) / TPB;   // 23

__global__ __launch_bounds__(512)
void imgs4dto3d_bin_kernel(const int* __restrict__ xyz,
                           int*       __restrict__ counts,
                           unsigned*  __restrict__ entries)
{
    const int b = blockIdx.x;
    const int e = threadIdx.x;
    const int x = xyz[(size_t)(b * E + e) * 3 + 0];
    const int y = xyz[(size_t)(b * E + e) * 3 + 1];
    const unsigned pk = (unsigned)e | ((unsigned)x << 9) | ((unsigned)y << 17);

    const int tr_lo = (x - HALF) >> 5, tr_hi = (x + HALF) >> 5;   // /32
    const int tc_lo = (y - HALF) >> 4, tc_hi = (y + HALF) >> 4;   // /16

    for (int tr = tr_lo; tr <= tr_hi; ++tr) {
        for (int tc = tc_lo; tc <= tc_hi; ++tc) {
            const int bin = b * NTILES + tr * NTC + tc;
            const int pos = atomicAdd(&counts[bin], 1);
            if (pos < CAP) entries[(size_t)bin * CAP + pos] = pk;
        }
    }
}

__global__ __launch_bounds__(THREADS, 4)
void imgs4dto3d_gather_kernel(const float*    __restrict__ img,
                              const int*      __restrict__ counts,
                              const unsigned* __restrict__ entries,
                              float*          __restrict__ out)
{
    const int b    = blockIdx.y;
    const int tid  = threadIdx.x;
    const int wid  = tid >> 6;
    const int lane = tid & 63;

    const int t    = blockIdx.x * TPB + wid;
    const bool live = (t < NTILES);
    const int tr = live ? (t / NTC) : 0;
    const int tc = live ? (t % NTC) : 0;
    const int r0 = tr * TRZ;
    const int c0 = tc * TCZ;

    // lane = (col 0..15) x (rowgroup 0..3); each lane owns 8 rows of one column
    const int col  = lane & 15;
    const int rowg = lane >> 4;
    const int c     = c0 + col;          // canvas col this lane owns
    const int rbase = r0 + rowg * 8;     // canvas rows rbase..rbase+7

    const int bin = live ? (b * NTILES + t) : 0;
    int n = live ? counts[bin] : 0;
    n = min(n, CAP);
    const uint4* lst = reinterpret_cast<const uint4*>(entries + (size_t)bin * CAP);

    const int rr = rbase + HALF;         // pr0 = rr - x
    const int cc = c + HALF;             // pc  = cc - y

    float acc[8] = {0.f, 0.f, 0.f, 0.f, 0.f, 0.f, 0.f, 0.f};
    const float* imgb = img + (size_t)b * E * (P * P);

    const int niter = (n + 3) >> 2;
    uint4 cur = (niter > 0) ? lst[0] : make_uint4(0u, 0u, 0u, 0u);
    for (int i = 0; i < niter; ++i) {
        const uint4 nxt = (i + 1 < niter) ? lst[i + 1] : cur;  // prefetch next entries
        const unsigned pks[4] = {cur.x, cur.y, cur.z, cur.w};
        #pragma unroll
        for (int u = 0; u < 4; ++u) {
            const bool inb = (4 * i + u) < n;        // wave-uniform
            const unsigned pk = pks[u];
            const int e = (int)(pk & 511u);
            const int x = (int)((pk >> 9) & 255u);
            const int y = (int)(pk >> 17);

            const int pc  = cc - y;                  // patch col (fixed per lane)
            const int pr0 = rr - x;                  // patch row for q=0
            const bool colok = inb && ((unsigned)pc <= 30u);

            // base pointer; per-q offset is a compile-time 31*q (folds into load imm)
            const float* bp = imgb + e * (P * P) + pr0 * P + pc;

            #pragma unroll
            for (int q = 0; q < 8; ++q) {
                const bool aq = colok && ((unsigned)(pr0 + q) <= 30u);
                acc[q] += aq ? bp[P * q] : 0.f;      // exec-masked predicated load
            }
        }
        cur = nxt;
    }

    // store: 8 scalar stores per lane (round-6 pattern; each pixel exactly once)
    if (live && c < S) {
        #pragma unroll
        for (int q = 0; q < 8; ++q) {
            const int r = rbase + q;
            if (r < S) {
                out[(size_t)b * (S * S) + r * S + c] = acc[q];
            }
        }
    }
}

extern "C" void kernel_launch(void* const* d_in, const int* in_sizes, int n_in,
                              void* d_out, int out_size, void* d_ws, size_t ws_size,
                              hipStream_t stream)
{
    const float* img = (const float*)d_in[0];   // [B, E, P, P] fp32
    const int*   xyz = (const int*)d_in[1];     // [B, E, 3] int32
    float*       out = (float*)d_out;           // [B, 1, S, S] fp32

    int*      counts  = (int*)d_ws;
    unsigned* entries = (unsigned*)d_ws + NBINS;

    hipMemsetAsync(counts, 0, (size_t)NBINS * sizeof(int), stream);

    imgs4dto3d_bin_kernel<<<B, E, 0, stream>>>(xyz, counts, entries);

    dim3 grid(NBLK, B);
    imgs4dto3d_gather_kernel<<<grid, THREADS, 0, stream>>>(img, counts, entries, out);
}